// Round 2
// baseline (109.856 us; speedup 1.0000x reference)
//
#include <hip/hip_runtime.h>

// B = in_sizes[0]/840, L=40, A=21. One thread per row; CPOS=1 chunks,
// LDS double-buffer + register prefetch (T14 async-stage), 1 barrier/chunk.
#define LPOS 40
#define AA   21
#define ROWF (LPOS*AA)        // 840 floats per row
#define ROWS 256              // rows per block
#define NTHR 256              // threads per block
#define CHF  (ROWS*AA)        // 5376 floats per chunk buffer
#define NIT  (CHF/NTHR)       // 21 staged elements per thread

__global__ __launch_bounds__(NTHR) void cm_kernel(
    const float* __restrict__ x,
    const float* __restrict__ vg,
    const float* __restrict__ jg,
    float* __restrict__ out)
{
    __shared__ float buf[2][CHF];   // 2 x 21504 B = 43008 B

    const int tid = threadIdx.x;
    const long long row0 = (long long)blockIdx.x * ROWS;
    const float* __restrict__ xb = x + row0 * ROWF;   // block base (uniform)

    // Per-thread staging offsets for chunk 0: f_i = tid + i*256,
    // r = f/21, e = f%21, goff = r*840 + e. Advance f by 256 => r+=12, e+=4.
    int goff[NIT];
    {
        int r = tid / AA;           // one magic-mul division, prologue only
        int e = tid - r * AA;
        int off = r * ROWF + e;
        #pragma unroll
        for (int i = 0; i < NIT; ++i) {
            goff[i] = off;
            e += 4; off += 12 * ROWF + 4;
            if (e >= AA) { e -= AA; off += ROWF - AA; }
        }
    }

    float rg[NIT];   // register staging for the in-flight chunk

    // Prologue: stage chunk 0 -> buf[0]; prefetch chunk 1 -> regs.
    #pragma unroll
    for (int i = 0; i < NIT; ++i) rg[i] = xb[goff[i]];
    #pragma unroll
    for (int i = 0; i < NIT; ++i) buf[0][tid + i * NTHR] = rg[i];
    #pragma unroll
    for (int i = 0; i < NIT; ++i) rg[i] = xb[AA + goff[i]];
    __syncthreads();

    float run = 1.0f, vsum = 0.0f, jsum = 0.0f;

    #pragma unroll 2
    for (int c = 0; c < LPOS; ++c) {
        // 1) write prefetched chunk c+1 into the idle buffer
        //    (its last readers finished before the barrier ending iter c-1)
        if (c < LPOS - 1) {
            float* __restrict__ bo = buf[(c + 1) & 1];
            #pragma unroll
            for (int i = 0; i < NIT; ++i) bo[tid + i * NTHR] = rg[i];
        }
        // 2) issue global loads for chunk c+2 (in flight across compute+barrier)
        if (c < LPOS - 2) {
            const float* __restrict__ xc = xb + (c + 2) * AA;
            #pragma unroll
            for (int i = 0; i < NIT; ++i) rg[i] = xc[goff[i]];
        }
        // 3) compute chunk c (stride-21 LDS reads: coprime with 32 banks -> conflict-free)
        {
            const float* __restrict__ xs = &buf[c & 1][tid * AA];
            float m = 0.0f;
            #pragma unroll
            for (int a = 0; a < AA; ++a) {
                const float xv = xs[a];
                m    = fmaf(xv, vg[c * AA + a], m);   // uniform -> scalar loads
                jsum = fmaf(xv, jg[c * AA + a], jsum);
            }
            run  *= m;
            vsum += run;
        }
        __syncthreads();
    }

    ((float2*)out)[row0 + tid] = make_float2(vsum, jsum);   // coalesced 8B store
}

extern "C" void kernel_launch(void* const* d_in, const int* in_sizes, int n_in,
                              void* d_out, int out_size, void* d_ws, size_t ws_size,
                              hipStream_t stream) {
    const float* x  = (const float*)d_in[0];
    const float* vg = (const float*)d_in[1];
    const float* jg = (const float*)d_in[2];
    float* out      = (float*)d_out;

    const int B    = in_sizes[0] / ROWF;   // 131072
    const int grid = B / ROWS;             // 512

    cm_kernel<<<grid, NTHR, 0, stream>>>(x, vg, jg, out);
}

// Round 5
// 86.662 us; speedup vs baseline: 1.2676x; 1.2676x over previous
//
#include <hip/hip_runtime.h>

// B = in_sizes[0]/840, L=40, A=21. One thread per row, ONE WAVE PER BLOCK
// (LDS wave-private, zero barriers). Single LDS chunk buffer; correctness =
// instruction order (enforced by compiler fences) + per-wave in-order DS.
// Depth-2 register prefetch with compile-time buffer names. float2 staging.
#define LPOS 40
#define AA   21
#define ROWF (LPOS*AA)        // 840 floats per row
#define CPOS 2
#define CF   (CPOS*AA)        // 42 floats per row-chunk
#define CF2  (CF/2)           // 21 float2 per row-chunk
#define NCH  (LPOS/CPOS)      // 20 chunks
#define NTHR 64               // one wave per block

// Compiler-only memory fence: no instructions emitted, but no memory op may
// cross it. This supplies the CROSS-LANE ordering the staging transpose
// needs (single-thread alias analysis would otherwise allow hoisting next
// chunk's ds_reads above this chunk's ds_writes — the R2/R3 failure).
// Hardware per-wave DS is in-order, so instruction order alone is correct.
#define FENCE() asm volatile("" ::: "memory")

__global__ __launch_bounds__(NTHR) void cm_kernel(
    const float* __restrict__ x,
    const float* __restrict__ vg,
    const float* __restrict__ jg,
    float* __restrict__ out)
{
    __shared__ float2 sbuf[NTHR * CF2];   // 10752 B, [64 rows][21 float2]

    const int lane = threadIdx.x;                       // 0..63
    const long long row0 = (long long)blockIdx.x * NTHR;
    const float2* xw2 = (const float2*)x + row0 * (ROWF / 2);

    // Per-lane float2 global offsets for chunk 0: flat slot f2 = lane + i*64
    // over [64 rows][21 float2]; r = f2/21, e = f2%21, goff = r*420 + e.
    // Step f2 += 64 => r += 3, e += 1 (wrap: e -= 21, r += 1).
    int goff[CF2];
    {
        int r = lane / AA;
        int e = lane - r * AA;
        int off = r * (ROWF / 2) + e;
        #pragma unroll
        for (int i = 0; i < CF2; ++i) {
            goff[i] = off;
            e += 1; off += 3 * (ROWF / 2) + 1;
            if (e >= AA) { e -= AA; off += (ROWF / 2) - AA; }
        }
    }

    float2 rgA[CF2], rgB[CF2];

    // Prologue: chunk0 -> rgA, chunk1 -> rgB (stays in flight), rgA -> LDS
    // (vmcnt waits only rgA), rgA <- chunk2.
    // Invariant entering c=0: LDS = chunk0; rgB = chunk1; rgA = chunk2.
    #pragma unroll
    for (int i = 0; i < CF2; ++i) rgA[i] = xw2[goff[i]];
    #pragma unroll
    for (int i = 0; i < CF2; ++i) rgB[i] = xw2[goff[i] + CF2];
    FENCE();
    #pragma unroll
    for (int i = 0; i < CF2; ++i) sbuf[lane + i * 64] = rgA[i];
    FENCE();
    #pragma unroll
    for (int i = 0; i < CF2; ++i) rgA[i] = xw2[goff[i] + 2 * CF2];
    FENCE();

    float run = 1.0f, vsum = 0.0f, jsum = 0.0f;

    // Body: compute chunk c from LDS; fence; overwrite LDS with chunk c+1
    // (WAR safe: reads issued first, DS pipe in-order); fence; refill RGW
    // with chunk c+3 (consumed again two bodies later -> depth-2 latency).
    #define BODY(c, RGW)                                                   \
      {                                                                    \
        const float* xs = (const float*)&sbuf[lane * CF2];                 \
        float m0 = 0.f, m1 = 0.f, jm = 0.f;                                \
        _Pragma("unroll")                                                  \
        for (int a = 0; a < AA; ++a) {                                     \
          const float x0 = xs[a];                                          \
          const float x1 = xs[AA + a];                                     \
          m0 = fmaf(x0, vg[(c) * CF + a], m0);        /* uniform s_load */ \
          m1 = fmaf(x1, vg[(c) * CF + AA + a], m1);                        \
          jm = fmaf(x0, jg[(c) * CF + a], jm);                             \
          jm = fmaf(x1, jg[(c) * CF + AA + a], jm);                        \
        }                                                                  \
        run *= m0; vsum += run;                                            \
        run *= m1; vsum += run;                                            \
        jsum += jm;                                                        \
        FENCE();                                                           \
        if ((c) + 1 < NCH) {                                               \
          _Pragma("unroll")                                                \
          for (int i = 0; i < CF2; ++i) sbuf[lane + i * 64] = RGW[i];      \
          FENCE();                                                         \
          if ((c) + 3 < NCH) {                                             \
            _Pragma("unroll")                                              \
            for (int i = 0; i < CF2; ++i)                                  \
              RGW[i] = xw2[goff[i] + ((c) + 3) * CF2];                     \
            FENCE();                                                       \
          }                                                                \
        }                                                                  \
      }

    for (int c = 0; c < NCH; c += 2) {
        BODY(c,     rgB)   // compute c;   stage c+1 (rgB); rgB <- c+3
        BODY(c + 1, rgA)   // compute c+1; stage c+2 (rgA); rgA <- c+4
    }

    ((float2*)out)[row0 + lane] = make_float2(vsum, jsum);  // coalesced 8B
}

extern "C" void kernel_launch(void* const* d_in, const int* in_sizes, int n_in,
                              void* d_out, int out_size, void* d_ws, size_t ws_size,
                              hipStream_t stream) {
    const float* x  = (const float*)d_in[0];
    const float* vg = (const float*)d_in[1];
    const float* jg = (const float*)d_in[2];
    float* out      = (float*)d_out;

    const int B    = in_sizes[0] / ROWF;   // 131072
    const int grid = B / NTHR;             // 2048

    cm_kernel<<<grid, NTHR, 0, stream>>>(x, vg, jg, out);
}